// Round 1
// baseline (548.519 us; speedup 1.0000x reference)
//
#include <hip/hip_runtime.h>

#define IN_C 128
#define H1   256
#define H2   32

// ---------------- init ----------------
__global__ __launch_bounds__(256) void k_init(int* deg, int* cursor, int* gtotal, int n) {
  int i = blockIdx.x * blockDim.x + threadIdx.x;
  if (i < n) { deg[i] = 1; cursor[i] = 0; }   // deg starts at 1: self-loop
  if (i == 0) *gtotal = 0;
}

// ---------------- degree count ----------------
__global__ __launch_bounds__(256) void k_deg(const int* __restrict__ dst, int* deg, int e) {
  int i = blockIdx.x * blockDim.x + threadIdx.x;
  if (i < e) atomicAdd(&deg[dst[i]], 1);
}

// ---------------- dinv + segment offsets (wave scan + 1 atomic/wave) ----------------
__global__ __launch_bounds__(256) void k_node_prep(const int* __restrict__ deg, float* __restrict__ dinv,
                                                   int* __restrict__ offsets, int* gtotal, int n) {
  int i = blockIdx.x * blockDim.x + threadIdx.x;
  int cnt = 0;
  if (i < n) {
    int d = deg[i];
    dinv[i] = rsqrtf((float)d);
    cnt = d - 1;                  // CSR holds only real edges; self-loop handled analytically
  }
  int lane = threadIdx.x & 63;
  int val = cnt;
  #pragma unroll
  for (int off = 1; off < 64; off <<= 1) {
    int t = __shfl_up(val, off, 64);
    if (lane >= off) val += t;
  }
  int wave_total = __shfl(val, 63, 64);
  int excl = val - cnt;
  int base = 0;
  if (lane == 63) base = atomicAdd(gtotal, wave_total);
  base = __shfl(base, 63, 64);
  if (i < n) offsets[i] = base + excl;
}

// ---------------- CSR fill (counting sort by dst) ----------------
__global__ __launch_bounds__(256) void k_fill(const int* __restrict__ src, const int* __restrict__ dst,
                                              const float* __restrict__ dinv, const int* __restrict__ offsets,
                                              int* cursor, int* __restrict__ csr_src,
                                              float* __restrict__ csr_coef, int e) {
  int i = blockIdx.x * blockDim.x + threadIdx.x;
  if (i < e) {
    int s = src[i], d = dst[i];
    int pos = atomicAdd(&cursor[d], 1);
    int idx = offsets[d] + pos;
    csr_src[idx] = s;
    csr_coef[idx] = dinv[s] * dinv[d];   // reused by BOTH conv layers
  }
}

// ---------------- layer-1 aggregation: agg1 = A @ x   (128 ch, 1 block/node) ----------------
__global__ __launch_bounds__(128) void k_agg1(const float* __restrict__ x, const float* __restrict__ dinv,
                                              const int* __restrict__ deg, const int* __restrict__ offsets,
                                              const int* __restrict__ csr_src, const float* __restrict__ csr_coef,
                                              float* __restrict__ agg, int n) {
  int node = blockIdx.x;
  int c = threadIdx.x;                       // 0..127
  float dn = dinv[node];
  float acc = x[(size_t)node * IN_C + c] * dn * dn;   // self-loop term
  int start = offsets[node];
  int cnt = deg[node] - 1;
  int j = 0;
  for (; j + 4 <= cnt; j += 4) {
    int   s0 = csr_src[start + j    ], s1 = csr_src[start + j + 1];
    int   s2 = csr_src[start + j + 2], s3 = csr_src[start + j + 3];
    float c0 = csr_coef[start + j    ], c1 = csr_coef[start + j + 1];
    float c2 = csr_coef[start + j + 2], c3 = csr_coef[start + j + 3];
    float x0 = x[(size_t)s0 * IN_C + c];
    float x1 = x[(size_t)s1 * IN_C + c];
    float x2 = x[(size_t)s2 * IN_C + c];
    float x3 = x[(size_t)s3 * IN_C + c];
    acc += x0 * c0 + x1 * c1 + x2 * c2 + x3 * c3;
  }
  for (; j < cnt; j++) {
    int s = csr_src[start + j];
    acc += x[(size_t)s * IN_C + c] * csr_coef[start + j];
  }
  agg[(size_t)node * IN_C + c] = acc;
}

// ---------------- GEMM1: h1 = relu(agg1 @ W1 + b1)   (8 nodes/block, 256 thr) ----------------
#define NPB1 8
__global__ __launch_bounds__(256) void k_gemm1(const float* __restrict__ agg, const float* __restrict__ W1,
                                               const float* __restrict__ b1, float* __restrict__ h1, int n) {
  __shared__ float rows[NPB1][IN_C];
  int nb = blockIdx.x * NPB1;
  for (int t = threadIdx.x; t < NPB1 * IN_C; t += 256) {
    int r = t >> 7, k = t & 127;
    int node = nb + r;
    rows[r][k] = (node < n) ? agg[(size_t)node * IN_C + k] : 0.f;
  }
  __syncthreads();
  int c = threadIdx.x;                       // output channel 0..255
  float bias = b1[c];
  float acc[NPB1];
  #pragma unroll
  for (int r = 0; r < NPB1; r++) acc[r] = bias;
  for (int k = 0; k < IN_C; k++) {
    float w = W1[k * H1 + c];                // coalesced; W1 L2-resident, reused x8
    #pragma unroll
    for (int r = 0; r < NPB1; r++) acc[r] += rows[r][k] * w;   // LDS broadcast reads
  }
  #pragma unroll
  for (int r = 0; r < NPB1; r++) {
    int node = nb + r;
    if (node < n) h1[(size_t)node * H1 + c] = fmaxf(acc[r], 0.f);
  }
}

// ---------------- GEMM2: h2 = h1 @ W2   (8 nodes/block, 256 thr = 8x32) ----------------
#define NPB2 8
__global__ __launch_bounds__(256) void k_gemm2(const float* __restrict__ h1, const float* __restrict__ W2,
                                               float* __restrict__ h2, int n) {
  __shared__ float rows[NPB2][H1 + 4];       // +4 pad: r-groups land on distinct banks
  int nb = blockIdx.x * NPB2;
  for (int t = threadIdx.x; t < NPB2 * H1; t += 256) {
    int r = t >> 8, k = t & 255;
    int node = nb + r;
    rows[r][k] = (node < n) ? h1[(size_t)node * H1 + k] : 0.f;
  }
  __syncthreads();
  int r = threadIdx.x >> 5, c = threadIdx.x & 31;
  float acc = 0.f;
  #pragma unroll 4
  for (int k = 0; k < H1; k++) acc += rows[r][k] * W2[k * H2 + c];
  int node = nb + r;
  if (node < n) h2[(size_t)node * H2 + c] = acc;   // bias applied after aggregation
}

// ---------------- layer-2 aggregation: z = A @ h2 + b2   (32 ch, 8 nodes/block) ----------------
__global__ __launch_bounds__(256) void k_agg2(const float* __restrict__ h2, const float* __restrict__ dinv,
                                              const int* __restrict__ deg, const int* __restrict__ offsets,
                                              const int* __restrict__ csr_src, const float* __restrict__ csr_coef,
                                              const float* __restrict__ b2, float* __restrict__ z, int n) {
  int node = blockIdx.x * 8 + (threadIdx.x >> 5);
  int c = threadIdx.x & 31;
  if (node >= n) return;
  float dn = dinv[node];
  float acc = h2[(size_t)node * H2 + c] * dn * dn;
  int start = offsets[node];
  int cnt = deg[node] - 1;
  int j = 0;
  for (; j + 4 <= cnt; j += 4) {
    int   s0 = csr_src[start + j    ], s1 = csr_src[start + j + 1];
    int   s2 = csr_src[start + j + 2], s3 = csr_src[start + j + 3];
    float c0 = csr_coef[start + j    ], c1 = csr_coef[start + j + 1];
    float c2 = csr_coef[start + j + 2], c3 = csr_coef[start + j + 3];
    acc += h2[(size_t)s0 * H2 + c] * c0 + h2[(size_t)s1 * H2 + c] * c1
         + h2[(size_t)s2 * H2 + c] * c2 + h2[(size_t)s3 * H2 + c] * c3;
  }
  for (; j < cnt; j++) {
    int s = csr_src[start + j];
    acc += h2[(size_t)s * H2 + c] * csr_coef[start + j];
  }
  z[(size_t)node * H2 + c] = acc + b2[c];
}

// ---------------- decode: out[p] = dot(z[a], z[b])   (32 lanes/pair) ----------------
__global__ __launch_bounds__(256) void k_decode(const float* __restrict__ z, const int* __restrict__ eli,
                                                float* __restrict__ out, int L) {
  int p = blockIdx.x * 8 + (threadIdx.x >> 5);
  int c = threadIdx.x & 31;
  if (p >= L) return;
  int a = eli[p], b = eli[L + p];
  float v = z[(size_t)a * H2 + c] * z[(size_t)b * H2 + c];
  #pragma unroll
  for (int off = 16; off >= 1; off >>= 1) v += __shfl_xor(v, off, 64);
  if (c == 0) out[p] = v;
}

extern "C" void kernel_launch(void* const* d_in, const int* in_sizes, int n_in,
                              void* d_out, int out_size, void* d_ws, size_t ws_size,
                              hipStream_t stream) {
  const float* x   = (const float*)d_in[0];
  const int*   ei  = (const int*)d_in[1];
  const int*   eli = (const int*)d_in[2];
  const float* W1  = (const float*)d_in[3];
  const float* b1  = (const float*)d_in[4];
  const float* W2  = (const float*)d_in[5];
  const float* b2  = (const float*)d_in[6];
  float* out = (float*)d_out;

  const int N = in_sizes[0] / IN_C;
  const int E = in_sizes[1] / 2;
  const int L = in_sizes[2] / 2;
  const int* e_src = ei;
  const int* e_dst = ei + E;

  // ---- workspace carve (aligned 256B). Total ~86.2 MB. ----
  char* p = (char*)d_ws;
  auto carve = [&](size_t bytes) -> void* {
    void* r = (void*)p;
    p += (bytes + 255) & ~(size_t)255;
    return r;
  };
  int*   deg      = (int*)  carve((size_t)N * 4);
  int*   cursor   = (int*)  carve((size_t)N * 4);
  float* dinv     = (float*)carve((size_t)N * 4);
  int*   offsets  = (int*)  carve((size_t)N * 4);
  int*   gtotal   = (int*)  carve(256);
  int*   csr_src  = (int*)  carve((size_t)E * 4);
  float* csr_coef = (float*)carve((size_t)E * 4);
  float* agg1     = (float*)carve((size_t)N * IN_C * 4);  // 25.6 MB; dead after gemm1
  float* h1       = (float*)carve((size_t)N * H1 * 4);    // 51.2 MB
  // alias h2 and z into agg1's space (agg1 no longer needed once gemm1 reads it)
  float* h2 = agg1;                                       // N*32*4 = 6.4 MB
  float* z  = agg1 + (size_t)N * H2;                      // next 6.4 MB

  const int B = 256;
  k_init<<<(N + B - 1) / B, B, 0, stream>>>(deg, cursor, gtotal, N);
  k_deg<<<(E + B - 1) / B, B, 0, stream>>>(e_dst, deg, E);
  k_node_prep<<<(N + B - 1) / B, B, 0, stream>>>(deg, dinv, offsets, gtotal, N);
  k_fill<<<(E + B - 1) / B, B, 0, stream>>>(e_src, e_dst, dinv, offsets, cursor, csr_src, csr_coef, E);
  k_agg1<<<N, IN_C, 0, stream>>>(x, dinv, deg, offsets, csr_src, csr_coef, agg1, N);
  k_gemm1<<<(N + NPB1 - 1) / NPB1, 256, 0, stream>>>(agg1, W1, b1, h1, N);
  k_gemm2<<<(N + NPB2 - 1) / NPB2, 256, 0, stream>>>(h1, W2, h2, N);
  k_agg2<<<(N + 7) / 8, 256, 0, stream>>>(h2, dinv, deg, offsets, csr_src, csr_coef, b2, z, N);
  k_decode<<<(L + 7) / 8, 256, 0, stream>>>(z, eli, out, L);
}